// Round 9
// baseline (4844.682 us; speedup 1.0000x reference)
//
#include <hip/hip_runtime.h>

#define HS 50
#define TT 512
#define GB 16          // batches per block (one wave, M=16)
#define NT 16          // N tiles: 4 gates x 4 j-tiles (N=256, j padded 50->64)

typedef _Float16 f16;
typedef _Float16 f16x8 __attribute__((ext_vector_type(8)));
typedef float    f32x4 __attribute__((ext_vector_type(4)));

__device__ __forceinline__ float fsig(float x) {
    return __builtin_amdgcn_rcpf(1.0f + __expf(-x));
}
__device__ __forceinline__ float ftanh(float x) {
    return 1.0f - 2.0f * __builtin_amdgcn_rcpf(__expf(2.0f * x) + 1.0f);
}

__global__ __launch_bounds__(64, 1) void lstm_mfma(
    const float* __restrict__ x,
    const float* __restrict__ wih1, const float* __restrict__ whh1,
    const float* __restrict__ bih1, const float* __restrict__ bhh1,
    const float* __restrict__ wih2, const float* __restrict__ whh2,
    const float* __restrict__ bih2, const float* __restrict__ bhh2,
    const float* __restrict__ fcw,  const float* __restrict__ fcb,
    float* __restrict__ out)
{
    // static LDS (dynamic >64KB needs opt-in attr; static up to 160KB is proven on this harness)
    __shared__ __align__(16) f16x8 wB[3 * NT * 2 * 64];   // 98304 B: B-frags [(mat*16+tile)*128 + kt*64 + lane]
    __shared__ __align__(16) f16   h1b[2 * 64 * 8];       // 2048 B: h1 A-frag buf
    __shared__ __align__(16) f16   h2b[2 * 64 * 8];       // 2048 B
    __shared__ __align__(16) float xl[GB * 513];          // 32832 B: x staged, padded stride

    const int lane = threadIdx.x;   // 0..63
    const int lr   = lane & 15;     // -> output col within tile / D-col (j)
    const int lq   = lane >> 4;     // -> k-group / row-quad
    const int gb0  = blockIdx.x * GB;

    // ---- one-time: pack weights into B-fragment order (assumed k = kt*32 + lq*8 + i;
    //      any within-k layout deviation cancels since A is packed with the same map) ----
    #pragma unroll
    for (int mat = 0; mat < 3; ++mat) {
        const float* ws = (mat == 0) ? whh1 : (mat == 1) ? wih2 : whh2;
        for (int ti = 0; ti < 32; ++ti) {           // tile*2 + kt
            int tile = ti >> 1, kt = ti & 1;
            int g = tile >> 2, jt = tile & 3;
            int j  = jt * 16 + lr;                  // output col (gate row of W)
            int k0 = kt * 32 + lq * 8;
            f16x8 v;
            #pragma unroll
            for (int i = 0; i < 8; ++i) {
                int k = k0 + i;
                float w = (j < HS && k < HS) ? ws[(g * HS + j) * HS + k] : 0.0f;
                v[i] = (f16)w;
            }
            wB[(mat * NT + tile) * 128 + kt * 64 + lane] = v;
        }
    }
    // ---- one-time: x preload (coalesced), padded row stride 513 to dodge bank aliasing ----
    for (int i = lane; i < GB * TT; i += 64)
        xl[(i >> 9) * 513 + (i & 511)] = x[(size_t)gb0 * TT + i];

    // ---- per-lane column constants ----
    float wih1v[NT], bs1v[NT], bs2v[NT];
    #pragma unroll
    for (int i = 0; i < NT; ++i) {
        int g = i >> 2, jt = i & 3;
        int j = jt * 16 + lr;
        bool valid = j < HS;
        int row = g * HS + (valid ? j : 0);
        wih1v[i] = valid ? wih1[row] : 0.0f;
        bs1v[i]  = valid ? bih1[row] + bhh1[row] : 0.0f;
        bs2v[i]  = valid ? bih2[row] + bhh2[row] : 0.0f;
    }
    float fcwv[4];
    #pragma unroll
    for (int jt = 0; jt < 4; ++jt) {
        int j = jt * 16 + lr;
        fcwv[jt] = (j < HS) ? fcw[j] : 0.0f;
    }

    // ---- state ----
    f16x8 hA1[2], hA2[2];
    #pragma unroll
    for (int kt = 0; kt < 2; ++kt)
        #pragma unroll
        for (int i = 0; i < 8; ++i) { hA1[kt][i] = (f16)0.0f; hA2[kt][i] = (f16)0.0f; }
    float c1[4][4], c2[4][4], h2v[4][4];
    #pragma unroll
    for (int jt = 0; jt < 4; ++jt)
        #pragma unroll
        for (int r = 0; r < 4; ++r) { c1[jt][r] = 0.f; c2[jt][r] = 0.f; h2v[jt][r] = 0.f; }

    const f16x8* h1bv = (const f16x8*)h1b;
    const f16x8* h2bv = (const f16x8*)h2b;

    #pragma unroll 1
    for (int t = 0; t < TT; ++t) {
        // x broadcast reads (4 distinct addrs, padded stride -> distinct banks)
        float xv[4];
        #pragma unroll
        for (int r = 0; r < 4; ++r) xv[r] = xl[(lq * 4 + r) * 513 + t];

        // ================= layer 1 =================
        f32x4 acc[NT];
        #pragma unroll
        for (int i = 0; i < NT; ++i) {
            #pragma unroll
            for (int r = 0; r < 4; ++r) acc[i][r] = fmaf(xv[r], wih1v[i], bs1v[i]);
        }
        #pragma unroll
        for (int kt = 0; kt < 2; ++kt) {
            #pragma unroll
            for (int i = 0; i < NT; ++i)
                acc[i] = __builtin_amdgcn_mfma_f32_16x16x32_f16(
                    hA1[kt], wB[(0 * NT + i) * 128 + kt * 64 + lane], acc[i], 0, 0, 0);
        }
        // activations (all 4 gates of (b,j) are lane-local by construction)
        float h1v[4][4];
        #pragma unroll
        for (int jt = 0; jt < 4; ++jt) {
            #pragma unroll
            for (int r = 0; r < 4; ++r) {
                float ig = fsig (acc[0 * 4 + jt][r]);
                float fg = fsig (acc[1 * 4 + jt][r]);
                float gg = ftanh(acc[2 * 4 + jt][r]);
                float og = fsig (acc[3 * 4 + jt][r]);
                float c  = fmaf(fg, c1[jt][r], ig * gg);
                c1[jt][r] = c;
                h1v[jt][r] = og * ftanh(c);
            }
        }
        // transpose h1 -> A-frag order; reload A-frags (single wave: no barrier)
        #pragma unroll
        for (int jt = 0; jt < 4; ++jt) {
            int j = jt * 16 + lr;
            int base = (jt >> 1) * 512 + 16 * ((j >> 3) & 3) * 8 + (j & 7);
            #pragma unroll
            for (int r = 0; r < 4; ++r)
                h1b[base + (lq * 4 + r) * 8] = (f16)h1v[jt][r];
        }
        hA1[0] = h1bv[lane];
        hA1[1] = h1bv[64 + lane];

        // ================= layer 2 =================
        #pragma unroll
        for (int i = 0; i < NT; ++i) {
            #pragma unroll
            for (int r = 0; r < 4; ++r) acc[i][r] = bs2v[i];
        }
        #pragma unroll
        for (int kt = 0; kt < 2; ++kt) {
            #pragma unroll
            for (int i = 0; i < NT; ++i)
                acc[i] = __builtin_amdgcn_mfma_f32_16x16x32_f16(
                    hA1[kt], wB[(1 * NT + i) * 128 + kt * 64 + lane], acc[i], 0, 0, 0);
        }
        #pragma unroll
        for (int kt = 0; kt < 2; ++kt) {
            #pragma unroll
            for (int i = 0; i < NT; ++i)
                acc[i] = __builtin_amdgcn_mfma_f32_16x16x32_f16(
                    hA2[kt], wB[(2 * NT + i) * 128 + kt * 64 + lane], acc[i], 0, 0, 0);
        }
        #pragma unroll
        for (int jt = 0; jt < 4; ++jt) {
            #pragma unroll
            for (int r = 0; r < 4; ++r) {
                float ig = fsig (acc[0 * 4 + jt][r]);
                float fg = fsig (acc[1 * 4 + jt][r]);
                float gg = ftanh(acc[2 * 4 + jt][r]);
                float og = fsig (acc[3 * 4 + jt][r]);
                float c  = fmaf(fg, c2[jt][r], ig * gg);
                c2[jt][r] = c;
                h2v[jt][r] = og * ftanh(c);
            }
        }
        #pragma unroll
        for (int jt = 0; jt < 4; ++jt) {
            int j = jt * 16 + lr;
            int base = (jt >> 1) * 512 + 16 * ((j >> 3) & 3) * 8 + (j & 7);
            #pragma unroll
            for (int r = 0; r < 4; ++r)
                h2b[base + (lq * 4 + r) * 8] = (f16)h2v[jt][r];
        }
        hA2[0] = h2bv[lane];
        hA2[1] = h2bv[64 + lane];
    }

    // ---- FC: out[b] = fcw . h2[b] + fcb ----
    float fcb0 = fcb[0];
    #pragma unroll
    for (int r = 0; r < 4; ++r) {
        float v = 0.0f;
        #pragma unroll
        for (int jt = 0; jt < 4; ++jt) v = fmaf(fcwv[jt], h2v[jt][r], v);
        #pragma unroll
        for (int off = 1; off < 16; off <<= 1) v += __shfl_xor(v, off);
        if (lr == 0) out[gb0 + lq * 4 + r] = v + fcb0;
    }
}

extern "C" void kernel_launch(void* const* d_in, const int* in_sizes, int n_in,
                              void* d_out, int out_size, void* d_ws, size_t ws_size,
                              hipStream_t stream) {
    const float* x    = (const float*)d_in[0];
    const float* wih1 = (const float*)d_in[1];
    const float* whh1 = (const float*)d_in[2];
    const float* bih1 = (const float*)d_in[3];
    const float* bhh1 = (const float*)d_in[4];
    const float* wih2 = (const float*)d_in[5];
    const float* whh2 = (const float*)d_in[6];
    const float* bih2 = (const float*)d_in[7];
    const float* bhh2 = (const float*)d_in[8];
    const float* fcw  = (const float*)d_in[9];
    const float* fcb  = (const float*)d_in[10];
    float* out = (float*)d_out;

    int B = in_sizes[0] / TT;                 // 4096
    int grid = B / GB;                        // 256 blocks, 1 wave each, 1 per CU
    hipLaunchKernelGGL(lstm_mfma, dim3(grid), dim3(64), 0, stream,
                       x, wih1, whh1, bih1, bhh1, wih2, whh2, bih2, bhh2, fcw, fcb, out);
}

// Round 11
// 2148.283 us; speedup vs baseline: 2.2551x; 2.2551x over previous
//
#include <hip/hip_runtime.h>

#define HS 50
#define TT 512
#define GB 16          // batches per block (one wave, M=16)
#define NT 16          // N tiles: 4 gates x 4 j-tiles (N=256, j padded 50->64)

typedef _Float16 f16;
typedef _Float16 f16x8 __attribute__((ext_vector_type(8)));
typedef float    f32x4 __attribute__((ext_vector_type(4)));

__device__ __forceinline__ float fsig(float x) {
    return __builtin_amdgcn_rcpf(1.0f + __expf(-x));
}
__device__ __forceinline__ float ftanh(float x) {
    return 1.0f - 2.0f * __builtin_amdgcn_rcpf(__expf(2.0f * x) + 1.0f);
}

__global__ __launch_bounds__(64, 1) void lstm_mfma(
    const float* __restrict__ x,
    const float* __restrict__ wih1, const float* __restrict__ whh1,
    const float* __restrict__ bih1, const float* __restrict__ bhh1,
    const float* __restrict__ wih2, const float* __restrict__ whh2,
    const float* __restrict__ bih2, const float* __restrict__ bhh2,
    const float* __restrict__ fcw,  const float* __restrict__ fcb,
    float* __restrict__ out)
{
    __shared__ __align__(16) f16x8 wB[3 * NT * 2 * 64];   // 98304 B
    __shared__ __align__(16) f16   h1b[2 * 64 * 8];       // 2048 B (A-frag order)
    __shared__ __align__(16) f16   h2b[2 * 64 * 8];       // 2048 B
    __shared__ __align__(16) float xl[GB * 513];          // 32832 B

    const int lane = threadIdx.x;   // 0..63
    const int lr   = lane & 15;
    const int lq   = lane >> 4;
    const int gb0  = blockIdx.x * GB;

    // ---- pack weights; K columns 50/51 carry bias / wih1 (A provides 1.0 / x there) ----
    #pragma unroll
    for (int mat = 0; mat < 3; ++mat) {
        const float* ws = (mat == 0) ? whh1 : (mat == 1) ? wih2 : whh2;
        for (int ti = 0; ti < 32; ++ti) {
            int tile = ti >> 1, kt = ti & 1;
            int g = tile >> 2, jt = tile & 3;
            int j  = jt * 16 + lr;
            int k0 = kt * 32 + lq * 8;
            int row = g * HS + (j < HS ? j : 0);
            f16x8 v;
            #pragma unroll
            for (int i = 0; i < 8; ++i) {
                int k = k0 + i;
                float w = 0.0f;
                if (j < HS) {
                    if (k < HS)                     w = ws[row * HS + k];
                    else if (k == 50) {
                        if (mat == 0)               w = bih1[row] + bhh1[row];
                        else if (mat == 2)          w = bih2[row] + bhh2[row];
                    } else if (k == 51 && mat == 0) w = wih1[row];
                }
                v[i] = (f16)w;
            }
            wB[(mat * NT + tile) * 128 + kt * 64 + lane] = v;
        }
    }
    // ---- x staging (coalesced), padded stride 513 ----
    for (int i = lane; i < GB * TT; i += 64)
        xl[(i >> 9) * 513 + (i & 511)] = x[(size_t)gb0 * TT + i];
    // ---- h buffers: zeros; slot k=50 = 1.0 (bias lane), h1b slot k=51 = x_0 ----
    for (int i = lane; i < 1024; i += 64) { h1b[i] = (f16)0.0f; h2b[i] = (f16)0.0f; }
    if (lane < 16) {
        h1b[512 + (lane + 32) * 8 + 2] = (f16)1.0f;   // (row=lane, k=50)
        h2b[512 + (lane + 32) * 8 + 2] = (f16)1.0f;
        h1b[512 + (lane + 32) * 8 + 3] = (f16)xl[lane * 513];  // (row=lane, k=51) = x_0
    }

    const f16x8* h1v8 = (const f16x8*)h1b;
    const f16x8* h2v8 = (const f16x8*)h2b;
    f16x8 hA1[2], hA2[2];
    hA1[0] = h1v8[lane]; hA1[1] = h1v8[64 + lane];
    hA2[0] = h2v8[lane]; hA2[1] = h2v8[64 + lane];

    float c1[4][4], c2[4][4], h2v[4][4];
    #pragma unroll
    for (int jt = 0; jt < 4; ++jt)
        #pragma unroll
        for (int r = 0; r < 4; ++r) { c1[jt][r] = 0.f; c2[jt][r] = 0.f; h2v[jt][r] = 0.f; }

    const f32x4 zero = {0.f, 0.f, 0.f, 0.f};

    #pragma unroll 1
    for (int t = 0; t < TT; ++t) {
        f32x4 acc[NT];
        // ===== layer 1: acc = whh1-pack * hA1  (bias + x*wih1 ride K slots 50/51) =====
        #pragma unroll
        for (int i = 0; i < NT; ++i)
            acc[i] = __builtin_amdgcn_mfma_f32_16x16x32_f16(
                hA1[0], wB[(0 * NT + i) * 128 + lane], zero, 0, 0, 0);
        #pragma unroll
        for (int i = 0; i < NT; ++i)
            acc[i] = __builtin_amdgcn_mfma_f32_16x16x32_f16(
                hA1[1], wB[(0 * NT + i) * 128 + 64 + lane], acc[i], 0, 0, 0);
        // ===== act L1 + guarded h1 writes =====
        #pragma unroll
        for (int jt = 0; jt < 4; ++jt) {
            int j = jt * 16 + lr;
            int base = (jt >> 1) * 512 + ((j >> 3) & 3) * 128 + (j & 7);
            #pragma unroll
            for (int r = 0; r < 4; ++r) {
                float ig = fsig (acc[0 * 4 + jt][r]);
                float fg = fsig (acc[1 * 4 + jt][r]);
                float gg = ftanh(acc[2 * 4 + jt][r]);
                float og = fsig (acc[3 * 4 + jt][r]);
                float c  = fmaf(fg, c1[jt][r], ig * gg);
                c1[jt][r] = c;
                float h = og * ftanh(c);
                if (j < HS) h1b[base + (lq * 4 + r) * 8] = (f16)h;
            }
        }
        // x_{t+1} into h1b slot k=51 (inert for L2: wih2 pack k>=50 is zero)
        int tn = (t + 1 < TT) ? t + 1 : TT - 1;
        if (lane < 16) h1b[512 + (lane + 32) * 8 + 3] = (f16)xl[lane * 513 + tn];
        // reload hA1 (latency covered by the whh2 chain below)
        hA1[0] = h1v8[lane]; hA1[1] = h1v8[64 + lane];

        // ===== layer 2: whh2 * h2_old first (hA2 already in regs), then wih2 * h1_new =====
        #pragma unroll
        for (int i = 0; i < NT; ++i)
            acc[i] = __builtin_amdgcn_mfma_f32_16x16x32_f16(
                hA2[0], wB[(2 * NT + i) * 128 + lane], zero, 0, 0, 0);
        #pragma unroll
        for (int i = 0; i < NT; ++i)
            acc[i] = __builtin_amdgcn_mfma_f32_16x16x32_f16(
                hA2[1], wB[(2 * NT + i) * 128 + 64 + lane], acc[i], 0, 0, 0);
        #pragma unroll
        for (int i = 0; i < NT; ++i)
            acc[i] = __builtin_amdgcn_mfma_f32_16x16x32_f16(
                hA1[0], wB[(1 * NT + i) * 128 + lane], acc[i], 0, 0, 0);
        #pragma unroll
        for (int i = 0; i < NT; ++i)
            acc[i] = __builtin_amdgcn_mfma_f32_16x16x32_f16(
                hA1[1], wB[(1 * NT + i) * 128 + 64 + lane], acc[i], 0, 0, 0);
        // ===== act L2 + guarded h2 writes =====
        #pragma unroll
        for (int jt = 0; jt < 4; ++jt) {
            int j = jt * 16 + lr;
            int base = (jt >> 1) * 512 + ((j >> 3) & 3) * 128 + (j & 7);
            #pragma unroll
            for (int r = 0; r < 4; ++r) {
                float ig = fsig (acc[0 * 4 + jt][r]);
                float fg = fsig (acc[1 * 4 + jt][r]);
                float gg = ftanh(acc[2 * 4 + jt][r]);
                float og = fsig (acc[3 * 4 + jt][r]);
                float c  = fmaf(fg, c2[jt][r], ig * gg);
                c2[jt][r] = c;
                float h = og * ftanh(c);
                h2v[jt][r] = h;
                if (j < HS) h2b[base + (lq * 4 + r) * 8] = (f16)h;
            }
        }
        // reload hA2 (consumed next iteration after the full L1 phase)
        hA2[0] = h2v8[lane]; hA2[1] = h2v8[64 + lane];
    }

    // ---- FC: out[b] = fcw . h2[b] + fcb ----
    float fcwv[4];
    #pragma unroll
    for (int jt = 0; jt < 4; ++jt) {
        int j = jt * 16 + lr;
        fcwv[jt] = (j < HS) ? fcw[j] : 0.0f;
    }
    float fcb0 = fcb[0];
    #pragma unroll
    for (int r = 0; r < 4; ++r) {
        float v = 0.0f;
        #pragma unroll
        for (int jt = 0; jt < 4; ++jt) v = fmaf(fcwv[jt], h2v[jt][r], v);
        #pragma unroll
        for (int off = 1; off < 16; off <<= 1) v += __shfl_xor(v, off);
        if (lr == 0) out[gb0 + lq * 4 + r] = v + fcb0;
    }
}

extern "C" void kernel_launch(void* const* d_in, const int* in_sizes, int n_in,
                              void* d_out, int out_size, void* d_ws, size_t ws_size,
                              hipStream_t stream) {
    const float* x    = (const float*)d_in[0];
    const float* wih1 = (const float*)d_in[1];
    const float* whh1 = (const float*)d_in[2];
    const float* bih1 = (const float*)d_in[3];
    const float* bhh1 = (const float*)d_in[4];
    const float* wih2 = (const float*)d_in[5];
    const float* whh2 = (const float*)d_in[6];
    const float* bih2 = (const float*)d_in[7];
    const float* bhh2 = (const float*)d_in[8];
    const float* fcw  = (const float*)d_in[9];
    const float* fcb  = (const float*)d_in[10];
    float* out = (float*)d_out;

    int B = in_sizes[0] / TT;                 // 4096
    int grid = B / GB;                        // 256 blocks, 1 wave each
    hipLaunchKernelGGL(lstm_mfma, dim3(grid), dim3(64), 0, stream,
                       x, wih1, whh1, bih1, bhh1, wih2, whh2, bih2, bhh2, fcw, fcb, out);
}

// Round 14
// 755.605 us; speedup vs baseline: 6.4117x; 2.8431x over previous
//
#include <hip/hip_runtime.h>

#define HS 50
#define TT 512
#define GB 16          // batches per block (shared by all 4 waves; MFMA M=16)
#define NT 16          // N tiles: 4 gates x 4 j-tiles; wave w owns jt=w
#define NW 4
#define BLOCK (NW*64)

typedef _Float16 f16;
typedef _Float16 f16x8 __attribute__((ext_vector_type(8)));
typedef float    f32x4 __attribute__((ext_vector_type(4)));

__device__ __forceinline__ float fsig(float x) {
    return __builtin_amdgcn_rcpf(1.0f + __expf(-x));
}
__device__ __forceinline__ float ftanh(float x) {
    return 1.0f - 2.0f * __builtin_amdgcn_rcpf(__expf(2.0f * x) + 1.0f);
}

__global__ __launch_bounds__(BLOCK, 1) void lstm_mfma4(
    const float* __restrict__ x,
    const float* __restrict__ wih1, const float* __restrict__ whh1,
    const float* __restrict__ bih1, const float* __restrict__ bhh1,
    const float* __restrict__ wih2, const float* __restrict__ whh2,
    const float* __restrict__ bih2, const float* __restrict__ bhh2,
    const float* __restrict__ fcw,  const float* __restrict__ fcb,
    float* __restrict__ out)
{
    __shared__ __align__(16) f16x8 wB[3 * NT * 2 * 64];   // 98304 B
    __shared__ __align__(16) f16   h1b[2 * 64 * 8];       // 2048 B (A-frag order)
    __shared__ __align__(16) f16   h2b[2 * 64 * 8];       // 2048 B
    __shared__ __align__(16) float xl[GB * 513];          // 32832 B
    __shared__ float fcpart[NW][GB];

    const int tid  = threadIdx.x;
    const int wid  = tid >> 6;
    const int lane = tid & 63;
    const int lr   = lane & 15;
    const int lq   = lane >> 4;
    const int gb0  = blockIdx.x * GB;

    // ---- pack weights (verified mapping; K cols 50/51 carry bias / wih1) ----
    #pragma unroll
    for (int mat = 0; mat < 3; ++mat) {
        const float* ws = (mat == 0) ? whh1 : (mat == 1) ? wih2 : whh2;
        for (int ti = wid; ti < 32; ti += NW) {
            int tile = ti >> 1, kt = ti & 1;
            int g = tile >> 2, jt = tile & 3;
            int j  = jt * 16 + lr;
            int k0 = kt * 32 + lq * 8;
            int row = g * HS + (j < HS ? j : 0);
            f16x8 v;
            #pragma unroll
            for (int i = 0; i < 8; ++i) {
                int k = k0 + i;
                float w = 0.0f;
                if (j < HS) {
                    if (k < HS)                     w = ws[row * HS + k];
                    else if (k == 50) {
                        if (mat == 0)               w = bih1[row] + bhh1[row];
                        else if (mat == 2)          w = bih2[row] + bhh2[row];
                    } else if (k == 51 && mat == 0) w = wih1[row];
                }
                v[i] = (f16)w;
            }
            wB[(mat * NT + tile) * 128 + kt * 64 + lane] = v;
        }
    }
    // ---- x staging (coalesced), padded stride 513 ----
    for (int i = tid; i < GB * TT; i += BLOCK)
        xl[(i >> 9) * 513 + (i & 511)] = x[(size_t)gb0 * TT + i];
    // ---- h buffers ----
    for (int i = tid; i < 1024; i += BLOCK) { h1b[i] = (f16)0.0f; h2b[i] = (f16)0.0f; }
    __syncthreads();
    if (tid < 16) {
        h1b[512 + (tid + 32) * 8 + 2] = (f16)1.0f;            // k=50 bias lane
        h2b[512 + (tid + 32) * 8 + 2] = (f16)1.0f;
        h1b[512 + (tid + 32) * 8 + 3] = (f16)xl[tid * 513];   // k=51 = x_0
    }
    __syncthreads();

    const f16x8* h1v8 = (const f16x8*)h1b;
    const f16x8* h2v8 = (const f16x8*)h2b;
    f16x8 hA1[2], hA2[2];
    hA1[0] = h1v8[lane]; hA1[1] = h1v8[64 + lane];
    hA2[0] = h2v8[lane]; hA2[1] = h2v8[64 + lane];

    float c1[4], c2[4], h2v[4];
    #pragma unroll
    for (int r = 0; r < 4; ++r) { c1[r] = 0.f; c2[r] = 0.f; h2v[r] = 0.f; }

    const int j     = wid * 16 + lr;                 // this wave's output column
    const int jbase = (wid >> 1) * 512 + ((j >> 3) & 3) * 128 + (j & 7);
    const bool jok  = j < HS;
    const f32x4 zero = {0.f, 0.f, 0.f, 0.f};

    #pragma unroll 1
    for (int t = 0; t < TT; ++t) {
        f32x4 acc[4];
        // ===== layer 1: tiles g*4+wid =====
        #pragma unroll
        for (int g = 0; g < 4; ++g)
            acc[g] = __builtin_amdgcn_mfma_f32_16x16x32_f16(
                hA1[0], wB[(0 * NT + g * 4 + wid) * 128 + lane], zero, 0, 0, 0);
        #pragma unroll
        for (int g = 0; g < 4; ++g)
            acc[g] = __builtin_amdgcn_mfma_f32_16x16x32_f16(
                hA1[1], wB[(0 * NT + g * 4 + wid) * 128 + 64 + lane], acc[g], 0, 0, 0);
        #pragma unroll
        for (int r = 0; r < 4; ++r) {
            float ig = fsig (acc[0][r]);
            float fg = fsig (acc[1][r]);
            float gg = ftanh(acc[2][r]);
            float og = fsig (acc[3][r]);
            float c  = fmaf(fg, c1[r], ig * gg);
            c1[r] = c;
            float h = og * ftanh(c);
            if (jok) h1b[jbase + (lq * 4 + r) * 8] = (f16)h;
        }
        int tn = (t + 1 < TT) ? t + 1 : TT - 1;
        if (tid < 16) h1b[512 + (tid + 32) * 8 + 3] = (f16)xl[tid * 513 + tn];
        __syncthreads();
        hA1[0] = h1v8[lane]; hA1[1] = h1v8[64 + lane];

        // ===== layer 2: whh2 * h2_old (regs), then wih2 * h1_new =====
        #pragma unroll
        for (int g = 0; g < 4; ++g)
            acc[g] = __builtin_amdgcn_mfma_f32_16x16x32_f16(
                hA2[0], wB[(2 * NT + g * 4 + wid) * 128 + lane], zero, 0, 0, 0);
        #pragma unroll
        for (int g = 0; g < 4; ++g)
            acc[g] = __builtin_amdgcn_mfma_f32_16x16x32_f16(
                hA2[1], wB[(2 * NT + g * 4 + wid) * 128 + 64 + lane], acc[g], 0, 0, 0);
        #pragma unroll
        for (int g = 0; g < 4; ++g)
            acc[g] = __builtin_amdgcn_mfma_f32_16x16x32_f16(
                hA1[0], wB[(1 * NT + g * 4 + wid) * 128 + lane], acc[g], 0, 0, 0);
        #pragma unroll
        for (int g = 0; g < 4; ++g)
            acc[g] = __builtin_amdgcn_mfma_f32_16x16x32_f16(
                hA1[1], wB[(1 * NT + g * 4 + wid) * 128 + 64 + lane], acc[g], 0, 0, 0);
        #pragma unroll
        for (int r = 0; r < 4; ++r) {
            float ig = fsig (acc[0][r]);
            float fg = fsig (acc[1][r]);
            float gg = ftanh(acc[2][r]);
            float og = fsig (acc[3][r]);
            float c  = fmaf(fg, c2[r], ig * gg);
            c2[r] = c;
            float h = og * ftanh(c);
            h2v[r] = h;
            if (jok) h2b[jbase + (lq * 4 + r) * 8] = (f16)h;
        }
        __syncthreads();
        hA2[0] = h2v8[lane]; hA2[1] = h2v8[64 + lane];
    }

    // ---- FC: partial per wave over its 16 j, then cross-wave sum ----
    float fcwj = jok ? fcw[j] : 0.0f;
    #pragma unroll
    for (int r = 0; r < 4; ++r) {
        float v = fcwj * h2v[r];
        v += __shfl_xor(v, 1); v += __shfl_xor(v, 2);
        v += __shfl_xor(v, 4); v += __shfl_xor(v, 8);
        if (lr == 0) fcpart[wid][lq * 4 + r] = v;
    }
    __syncthreads();
    if (tid < GB)
        out[gb0 + tid] = fcpart[0][tid] + fcpart[1][tid] + fcpart[2][tid] + fcpart[3][tid] + fcb[0];
}

extern "C" void kernel_launch(void* const* d_in, const int* in_sizes, int n_in,
                              void* d_out, int out_size, void* d_ws, size_t ws_size,
                              hipStream_t stream) {
    const float* x    = (const float*)d_in[0];
    const float* wih1 = (const float*)d_in[1];
    const float* whh1 = (const float*)d_in[2];
    const float* bih1 = (const float*)d_in[3];
    const float* bhh1 = (const float*)d_in[4];
    const float* wih2 = (const float*)d_in[5];
    const float* whh2 = (const float*)d_in[6];
    const float* bih2 = (const float*)d_in[7];
    const float* bhh2 = (const float*)d_in[8];
    const float* fcw  = (const float*)d_in[9];
    const float* fcb  = (const float*)d_in[10];
    float* out = (float*)d_out;

    int B = in_sizes[0] / TT;                 // 4096
    int grid = B / GB;                        // 256 blocks, 4 waves each, 1 block/CU
    hipLaunchKernelGGL(lstm_mfma4, dim3(grid), dim3(BLOCK), 0, stream,
                       x, wih1, whh1, bih1, bhh1, wih2, whh2, bih2, bhh2, fcw, fcb, out);
}